// Round 1
// 335.844 us; speedup vs baseline: 1.0561x; 1.0561x over previous
//
#include <hip/hip_runtime.h>

#define KK 16
#define DD 15          // K-1
#define NPIX (2048*2048)

typedef float v4f __attribute__((ext_vector_type(4)));

__global__ __launch_bounds__(256, 4) void gum_kernel(
    const float* __restrict__ z,      // (DD, NPIX)
    const float* __restrict__ vert,   // (KK, DD) row-major
    float* __restrict__ out)          // [0,NPIX) = X as float, [NPIX,2*NPIX) = dmin
{
    // Only ||v_k||^2 in LDS (broadcast ds_read_b32). Vertex components are
    // uniform-indexed -> s_load -> SGPR operand folded into v_pk_fma.
    __shared__ float vvS[KK];

    const int t = threadIdx.x;
    if (t < KK) {
        float s = 0.0f;
        #pragma unroll
        for (int d = 0; d < DD; ++d) {
            float v = vert[t * DD + d];
            s += v * v;
        }
        vvS[t] = s;
    }
    __syncthreads();

    const int gid  = blockIdx.x * blockDim.x + t;  // pixel-quad id
    const size_t base = (size_t)gid * 4;

    // 15 independent dwordx4 loads, all in flight (saddr form: per-plane base
    // in SGPRs, shared voffset). 4 px/thread = 16 B/lane coalescing sweet spot
    // (1 KiB per wave instruction per plane stream). zv = 60 VGPRs -> ~90 total,
    // 4 waves/SIMD; bytes-in-flight per SIMD identical to the 2px/8-wave version.
    // nt loads: z is stream-once, skip cache allocation.
    v4f zv[DD];
    #pragma unroll
    for (int d = 0; d < DD; ++d)
        zv[d] = __builtin_nontemporal_load((const v4f*)(z + (size_t)d * NPIX + base));

    v4f zz = {0.f, 0.f, 0.f, 0.f};
    #pragma unroll
    for (int d = 0; d < DD; ++d)
        zz += zv[d] * zv[d];                       // v_pk_fma_f32 pairs

    v4f bestd2 = {3.0e38f, 3.0e38f, 3.0e38f, 3.0e38f};
    int bk0 = 0, bk1 = 0, bk2 = 0, bk3 = 0;

    #pragma unroll
    for (int k = 0; k < KK; ++k) {
        v4f cr = {0.f, 0.f, 0.f, 0.f};
        #pragma unroll
        for (int d = 0; d < DD; ++d) {
            const float vkd = vert[k * DD + d];    // scalar (SGPR) broadcast
            cr += vkd * zv[d];                     // v_pk_fma_f32, SGPR src splat
        }
        const float vvk = vvS[k];
        // same evaluation order as ref: (zz - 2*cross) + vv; argmin on d^2
        // (sqrt monotone & correctly rounded -> identical argmin/min).
        v4f d2 = (zz - 2.0f * cr) + vvk;
        if (d2.x < bestd2.x) { bestd2.x = d2.x; bk0 = k; }  // first-min tie-break
        if (d2.y < bestd2.y) { bestd2.y = d2.y; bk1 = k; }
        if (d2.z < bestd2.z) { bestd2.z = d2.z; bk2 = k; }
        if (d2.w < bestd2.w) { bestd2.w = d2.w; bk3 = k; }
    }

    v4f xo, dm;
    xo.x = (float)bk0;
    xo.y = (float)bk1;
    xo.z = (float)bk2;
    xo.w = (float)bk3;
    dm.x = sqrtf(fmaxf(bestd2.x, 0.0f));
    dm.y = sqrtf(fmaxf(bestd2.y, 0.0f));
    dm.z = sqrtf(fmaxf(bestd2.z, 0.0f));
    dm.w = sqrtf(fmaxf(bestd2.w, 0.0f));

    // nt stores: out is write-once — don't evict L3-resident data.
    __builtin_nontemporal_store(xo, (v4f*)(out + base));
    __builtin_nontemporal_store(dm, (v4f*)(out + NPIX + base));
}

extern "C" void kernel_launch(void* const* d_in, const int* in_sizes, int n_in,
                              void* d_out, int out_size, void* d_ws, size_t ws_size,
                              hipStream_t stream) {
    const float* z    = (const float*)d_in[0];   // (15, 2048, 2048) fp32
    const float* vert = (const float*)d_in[1];   // (16, 15) fp32
    float* out = (float*)d_out;                  // 2 * NPIX floats

    const int npix    = in_sizes[0] / DD;        // 4194304
    const int threads = 256;
    const int quads   = npix / 4;                // 4 pixels per thread
    const int blocks  = (quads + threads - 1) / threads;   // 4096

    gum_kernel<<<blocks, threads, 0, stream>>>(z, vert, out);
}

// Round 2
// 333.411 us; speedup vs baseline: 1.0638x; 1.0073x over previous
//
#include <hip/hip_runtime.h>

#define KK 16
#define DD 15          // K-1
#define NPIX (2048*2048)

typedef float v4f __attribute__((ext_vector_type(4)));

__global__ __launch_bounds__(256, 2) void gum_kernel(
    const float* __restrict__ z,      // (DD, NPIX)
    const float* __restrict__ vert,   // (KK, DD) row-major
    float* __restrict__ out)          // [0,NPIX) = X as float, [NPIX,2*NPIX) = dmin
{
    // Only ||v_k||^2 in LDS (broadcast ds_read_b32). Vertex components are
    // uniform-indexed -> s_load -> SGPR operand folded into v_pk_fma.
    __shared__ float vvS[KK];

    const int t = threadIdx.x;
    if (t < KK) {
        float s = 0.0f;
        #pragma unroll
        for (int d = 0; d < DD; ++d) {
            float v = vert[t * DD + d];
            s += v * v;
        }
        vvS[t] = s;
    }
    __syncthreads();

    const int gid  = blockIdx.x * blockDim.x + t;  // pixel-octet id
    const size_t base = (size_t)gid * 8;

    // 8 px/thread: 30 independent dwordx4 loads all in flight (2 KiB per
    // plane stream per wave). Halves wave count vs 4px (8192 waves total,
    // half the prologue/barrier overhead); bytes-in-flight per SIMD
    // unchanged (2 waves x 30 KiB == 4 x 15 KiB). zv = 120 VGPRs -> ~180
    // total, 2 waves/SIMD — still memory-bound with full overlap
    // (compute ~2.4k cy/wave << memory ~22k cy at per-SIMD BW share).
    // nt loads: z is stream-once, skip cache allocation.
    v4f zva[DD], zvb[DD];
    #pragma unroll
    for (int d = 0; d < DD; ++d) {
        const float* p = z + (size_t)d * NPIX + base;
        zva[d] = __builtin_nontemporal_load((const v4f*)p);
        zvb[d] = __builtin_nontemporal_load((const v4f*)(p + 4));
    }

    v4f zza = {0.f, 0.f, 0.f, 0.f};
    v4f zzb = {0.f, 0.f, 0.f, 0.f};
    #pragma unroll
    for (int d = 0; d < DD; ++d) {
        zza += zva[d] * zva[d];                    // v_pk_fma_f32 pairs
        zzb += zvb[d] * zvb[d];
    }

    v4f bda = {3.0e38f, 3.0e38f, 3.0e38f, 3.0e38f};
    v4f bdb = {3.0e38f, 3.0e38f, 3.0e38f, 3.0e38f};
    int bka0 = 0, bka1 = 0, bka2 = 0, bka3 = 0;
    int bkb0 = 0, bkb1 = 0, bkb2 = 0, bkb3 = 0;

    #pragma unroll
    for (int k = 0; k < KK; ++k) {
        v4f cra = {0.f, 0.f, 0.f, 0.f};
        v4f crb = {0.f, 0.f, 0.f, 0.f};
        #pragma unroll
        for (int d = 0; d < DD; ++d) {
            const float vkd = vert[k * DD + d];    // scalar (SGPR) broadcast
            cra += vkd * zva[d];                   // v_pk_fma_f32, SGPR src splat
            crb += vkd * zvb[d];
        }
        const float vvk = vvS[k];
        // same evaluation order as ref: (zz - 2*cross) + vv; argmin on d^2
        // (sqrt monotone & correctly rounded -> identical argmin/min).
        v4f d2a = (zza - 2.0f * cra) + vvk;
        v4f d2b = (zzb - 2.0f * crb) + vvk;
        if (d2a.x < bda.x) { bda.x = d2a.x; bka0 = k; }  // first-min tie-break
        if (d2a.y < bda.y) { bda.y = d2a.y; bka1 = k; }
        if (d2a.z < bda.z) { bda.z = d2a.z; bka2 = k; }
        if (d2a.w < bda.w) { bda.w = d2a.w; bka3 = k; }
        if (d2b.x < bdb.x) { bdb.x = d2b.x; bkb0 = k; }
        if (d2b.y < bdb.y) { bdb.y = d2b.y; bkb1 = k; }
        if (d2b.z < bdb.z) { bdb.z = d2b.z; bkb2 = k; }
        if (d2b.w < bdb.w) { bdb.w = d2b.w; bkb3 = k; }
    }

    v4f xoa, xob, dma, dmb;
    xoa.x = (float)bka0; xoa.y = (float)bka1; xoa.z = (float)bka2; xoa.w = (float)bka3;
    xob.x = (float)bkb0; xob.y = (float)bkb1; xob.z = (float)bkb2; xob.w = (float)bkb3;
    dma.x = sqrtf(fmaxf(bda.x, 0.0f));
    dma.y = sqrtf(fmaxf(bda.y, 0.0f));
    dma.z = sqrtf(fmaxf(bda.z, 0.0f));
    dma.w = sqrtf(fmaxf(bda.w, 0.0f));
    dmb.x = sqrtf(fmaxf(bdb.x, 0.0f));
    dmb.y = sqrtf(fmaxf(bdb.y, 0.0f));
    dmb.z = sqrtf(fmaxf(bdb.z, 0.0f));
    dmb.w = sqrtf(fmaxf(bdb.w, 0.0f));

    // nt stores: out is write-once — don't evict L3-resident data.
    __builtin_nontemporal_store(xoa, (v4f*)(out + base));
    __builtin_nontemporal_store(xob, (v4f*)(out + base + 4));
    __builtin_nontemporal_store(dma, (v4f*)(out + NPIX + base));
    __builtin_nontemporal_store(dmb, (v4f*)(out + NPIX + base + 4));
}

extern "C" void kernel_launch(void* const* d_in, const int* in_sizes, int n_in,
                              void* d_out, int out_size, void* d_ws, size_t ws_size,
                              hipStream_t stream) {
    const float* z    = (const float*)d_in[0];   // (15, 2048, 2048) fp32
    const float* vert = (const float*)d_in[1];   // (16, 15) fp32
    float* out = (float*)d_out;                  // 2 * NPIX floats

    const int npix    = in_sizes[0] / DD;        // 4194304
    const int threads = 256;
    const int octs    = npix / 8;                // 8 pixels per thread
    const int blocks  = (octs + threads - 1) / threads;    // 2048

    gum_kernel<<<blocks, threads, 0, stream>>>(z, vert, out);
}